// Round 1
// baseline (264.911 us; speedup 1.0000x reference)
//
#include <hip/hip_runtime.h>
#include <stdint.h>

#define K_DIM 4096
#define N_DIM 4096
#define M_DIM 8192   // B*S = 4*2048
#define S_ROWS 2048
#define NBATCH 4

typedef int v4i __attribute__((ext_vector_type(4)));

__device__ __forceinline__ void gload16(const void* g, void* l) {
    __builtin_amdgcn_global_load_lds(
        (const __attribute__((address_space(1))) unsigned int*)g,
        (__attribute__((address_space(3))) unsigned int*)l, 16, 0, 0);
}

// ---------------- 1. per-batch absmax ----------------
// grid (1024, 4) x 256 threads; each thread: 8 float4
__global__ void absmax_kernel(const float* __restrict__ x, unsigned* __restrict__ amax) {
    int b = blockIdx.y;
    const float4* xb = (const float4*)(x + (size_t)b * S_ROWS * K_DIM);
    int tid = blockIdx.x * 256 + threadIdx.x;   // 0..262143
    const int stride = 1024 * 256;
    float m = 0.f;
#pragma unroll
    for (int i = 0; i < 8; ++i) {
        float4 v = xb[tid + i * stride];
        m = fmaxf(m, fmaxf(fmaxf(fabsf(v.x), fabsf(v.y)),
                           fmaxf(fabsf(v.z), fabsf(v.w))));
    }
#pragma unroll
    for (int off = 32; off; off >>= 1)
        m = fmaxf(m, __shfl_xor(m, off));
    __shared__ float red[4];
    if ((threadIdx.x & 63) == 0) red[threadIdx.x >> 6] = m;
    __syncthreads();
    if (threadIdx.x == 0) {
        m = fmaxf(fmaxf(red[0], red[1]), fmaxf(red[2], red[3]));
        atomicMax(&amax[b], __float_as_uint(m));
    }
}

// ---------------- 2. quantize x -> int8 ----------------
// grid 8192 x 256; 16 elements/thread
__global__ void quant_kernel(const float* __restrict__ x,
                             const unsigned* __restrict__ amax,
                             char* __restrict__ xq) {
    size_t gid = (size_t)blockIdx.x * 256 + threadIdx.x;   // 0..2097151
    size_t base = gid * 16;
    int b = (int)(base >> 23);                              // 2048*4096 = 2^23 per batch
    float inv = 128.0f / __uint_as_float(amax[b]);
    const float4* xs = (const float4*)(x + base);
    unsigned parts[4];
#pragma unroll
    for (int i = 0; i < 4; ++i) {
        float4 v = xs[i];
        int q0 = max(-128, min(127, (int)rintf(v.x * inv)));
        int q1 = max(-128, min(127, (int)rintf(v.y * inv)));
        int q2 = max(-128, min(127, (int)rintf(v.z * inv)));
        int q3 = max(-128, min(127, (int)rintf(v.w * inv)));
        parts[i] = (q0 & 255) | ((q1 & 255) << 8) | ((q2 & 255) << 16) | ((q3 & 255) << 24);
    }
    *(uint4*)(xq + base) = make_uint4(parts[0], parts[1], parts[2], parts[3]);
}

// ---------------- 3. weight pack + transpose: int32 [K][N] -> int8 [N][K] ----------------
// grid (64, 64) x 256; 64x64 tile
__global__ void wtrans_kernel(const int* __restrict__ wq, char* __restrict__ wt) {
    __shared__ unsigned lds[64 * 17];   // [n-col][16 packed u32 + pad]
    int t = threadIdx.x;
    int c = t & 63;          // n within tile
    int g = t >> 6;          // 0..3
    int n0 = blockIdx.x * 64;
    int k0 = blockIdx.y * 64;
#pragma unroll
    for (int rep = 0; rep < 4; ++rep) {
        int kb = g * 16 + rep * 4;   // 4 consecutive k rows
        int v0 = wq[(size_t)(k0 + kb + 0) * N_DIM + n0 + c];
        int v1 = wq[(size_t)(k0 + kb + 1) * N_DIM + n0 + c];
        int v2 = wq[(size_t)(k0 + kb + 2) * N_DIM + n0 + c];
        int v3 = wq[(size_t)(k0 + kb + 3) * N_DIM + n0 + c];
        lds[c * 17 + (kb >> 2)] =
            (v0 & 255) | ((v1 & 255) << 8) | ((v2 & 255) << 16) | ((v3 & 255) << 24);
    }
    __syncthreads();
    int row = t >> 2;        // n within tile
    int ch = t & 3;          // 16B chunk along k
    uint4 o;
    o.x = lds[row * 17 + ch * 4 + 0];
    o.y = lds[row * 17 + ch * 4 + 1];
    o.z = lds[row * 17 + ch * 4 + 2];
    o.w = lds[row * 17 + ch * 4 + 3];
    *(uint4*)(wt + (size_t)(n0 + row) * K_DIM + k0 + ch * 16) = o;
}

// ---------------- 4. int8 MFMA GEMM + dequant + bias ----------------
// BM=BN=128, BK=64. 4 waves (2x2), each wave 64x64 = 4x4 fragments of 16x16.
// A [M][K] i8, Bt [N][K] i8, both staged via global_load_lds with pre-swizzled
// source (slot ^= (row>>1)&3) so ds_read_b128 fragment reads are ~conflict-free.
__global__ void gemm_kernel(const char* __restrict__ A,
                            const char* __restrict__ Bt,
                            const float* __restrict__ bias,
                            const unsigned* __restrict__ amax,
                            float* __restrict__ out) {
    __shared__ char As[128 * 64];
    __shared__ char Bs[128 * 64];
    int t = threadIdx.x;
    int l = t & 63;
    int w = t >> 6;
    int wm = w >> 1, wn = w & 1;
    int m0 = blockIdx.y * 128;
    int n0 = blockIdx.x * 128;

    v4i acc[4][4];
#pragma unroll
    for (int i = 0; i < 4; ++i)
#pragma unroll
        for (int j = 0; j < 4; ++j)
            acc[i][j] = (v4i){0, 0, 0, 0};

    int sk = l >> 4;       // 16B k-slot within a 64B row
    int rb = l & 15;

    for (int kt = 0; kt < K_DIM; kt += 64) {
#pragma unroll
        for (int i = 0; i < 2; ++i) {
            int p = (w * 2 + i) * 64 + l;           // linear 16B slot 0..511
            int r = p >> 2;                          // tile row
            int s = (p & 3) ^ ((r >> 1) & 3);        // inverse-swizzled source slot
            gload16(A + (size_t)(m0 + r) * K_DIM + kt + s * 16, As + p * 16);
            gload16(Bt + (size_t)(n0 + r) * K_DIM + kt + s * 16, Bs + p * 16);
        }
        __syncthreads();

        v4i a[4], bf[4];
#pragma unroll
        for (int mi = 0; mi < 4; ++mi) {
            int row = wm * 64 + mi * 16 + rb;
            a[mi] = *(const v4i*)(As + row * 64 + ((sk ^ ((row >> 1) & 3)) << 4));
        }
#pragma unroll
        for (int ni = 0; ni < 4; ++ni) {
            int row = wn * 64 + ni * 16 + rb;
            bf[ni] = *(const v4i*)(Bs + row * 64 + ((sk ^ ((row >> 1) & 3)) << 4));
        }
#pragma unroll
        for (int mi = 0; mi < 4; ++mi)
#pragma unroll
            for (int ni = 0; ni < 4; ++ni)
                acc[mi][ni] = __builtin_amdgcn_mfma_i32_16x16x64_i8(
                    a[mi], bf[ni], acc[mi][ni], 0, 0, 0);
        __syncthreads();
    }

    // epilogue: y = acc * (x_scale * 0.01) + bias
    float scale = __uint_as_float(amax[m0 >> 11]) * (1.0f / 128.0f) * 0.01f;
    int colb = n0 + wn * 64 + (l & 15);
    int rowb = m0 + wm * 64 + (l >> 4) * 4;
#pragma unroll
    for (int ni = 0; ni < 4; ++ni) {
        float bv = bias[colb + ni * 16];
#pragma unroll
        for (int mi = 0; mi < 4; ++mi) {
#pragma unroll
            for (int rg = 0; rg < 4; ++rg) {
                out[(size_t)(rowb + mi * 16 + rg) * N_DIM + colb + ni * 16] =
                    (float)acc[mi][ni][rg] * scale + bv;
            }
        }
    }
}

extern "C" void kernel_launch(void* const* d_in, const int* in_sizes, int n_in,
                              void* d_out, int out_size, void* d_ws, size_t ws_size,
                              hipStream_t stream) {
    const float* x = (const float*)d_in[0];
    const int* wq = (const int*)d_in[1];
    const float* bias = (const float*)d_in[2];
    float* out = (float*)d_out;

    unsigned* amax = (unsigned*)d_ws;
    char* xq = (char*)d_ws + 256;
    char* wt = (char*)d_ws + 256 + (size_t)M_DIM * K_DIM;

    hipMemsetAsync(d_ws, 0, 16, stream);

    wtrans_kernel<<<dim3(64, 64), 256, 0, stream>>>(wq, wt);
    absmax_kernel<<<dim3(1024, 4), 256, 0, stream>>>(x, amax);
    quant_kernel<<<8192, 256, 0, stream>>>(x, amax, xq);
    gemm_kernel<<<dim3(32, 64), 256, 0, stream>>>(xq, wt, bias, amax, out);
}

// Round 2
// 236.404 us; speedup vs baseline: 1.1206x; 1.1206x over previous
//
#include <hip/hip_runtime.h>
#include <stdint.h>

#define K_DIM 4096
#define N_DIM 4096
#define M_DIM 8192   // B*S = 4*2048
#define S_ROWS 2048
#define NT 32        // K tiles of 128

typedef int v4i __attribute__((ext_vector_type(4)));

__device__ __forceinline__ void gload16(const void* g, void* l) {
    __builtin_amdgcn_global_load_lds(
        (const __attribute__((address_space(1))) unsigned int*)g,
        (__attribute__((address_space(3))) unsigned int*)l, 16, 0, 0);
}

__device__ __forceinline__ void barrier() {
    asm volatile("" ::: "memory");
    __builtin_amdgcn_s_barrier();
    asm volatile("" ::: "memory");
}

// ---------------- 1. per-batch absmax ----------------
__global__ void absmax_kernel(const float* __restrict__ x, unsigned* __restrict__ amax) {
    int b = blockIdx.y;
    const float4* xb = (const float4*)(x + (size_t)b * S_ROWS * K_DIM);
    int tid = blockIdx.x * 256 + threadIdx.x;
    const int stride = 1024 * 256;
    float m = 0.f;
#pragma unroll
    for (int i = 0; i < 8; ++i) {
        float4 v = xb[tid + i * stride];
        m = fmaxf(m, fmaxf(fmaxf(fabsf(v.x), fabsf(v.y)),
                           fmaxf(fabsf(v.z), fabsf(v.w))));
    }
#pragma unroll
    for (int off = 32; off; off >>= 1)
        m = fmaxf(m, __shfl_xor(m, off));
    __shared__ float red[4];
    if ((threadIdx.x & 63) == 0) red[threadIdx.x >> 6] = m;
    __syncthreads();
    if (threadIdx.x == 0) {
        m = fmaxf(fmaxf(red[0], red[1]), fmaxf(red[2], red[3]));
        atomicMax(&amax[b], __float_as_uint(m));
    }
}

// ---------------- 2. quantize x -> int8 ----------------
__global__ void quant_kernel(const float* __restrict__ x,
                             const unsigned* __restrict__ amax,
                             char* __restrict__ xq) {
    size_t gid = (size_t)blockIdx.x * 256 + threadIdx.x;
    size_t base = gid * 16;
    int b = (int)(base >> 23);
    float inv = 128.0f / __uint_as_float(amax[b]);
    const float4* xs = (const float4*)(x + base);
    unsigned parts[4];
#pragma unroll
    for (int i = 0; i < 4; ++i) {
        float4 v = xs[i];
        int q0 = max(-128, min(127, (int)rintf(v.x * inv)));
        int q1 = max(-128, min(127, (int)rintf(v.y * inv)));
        int q2 = max(-128, min(127, (int)rintf(v.z * inv)));
        int q3 = max(-128, min(127, (int)rintf(v.w * inv)));
        parts[i] = (q0 & 255) | ((q1 & 255) << 8) | ((q2 & 255) << 16) | ((q3 & 255) << 24);
    }
    *(uint4*)(xq + base) = make_uint4(parts[0], parts[1], parts[2], parts[3]);
}

// ---------------- 3. weight pack + transpose: int32 [K][N] -> int8 [N][K] ----------------
__global__ void wtrans_kernel(const int* __restrict__ wq, char* __restrict__ wt) {
    __shared__ unsigned lds[64 * 17];
    int t = threadIdx.x;
    int c = t & 63;
    int g = t >> 6;
    int n0 = blockIdx.x * 64;
    int k0 = blockIdx.y * 64;
#pragma unroll
    for (int rep = 0; rep < 4; ++rep) {
        int kb = g * 16 + rep * 4;
        int v0 = wq[(size_t)(k0 + kb + 0) * N_DIM + n0 + c];
        int v1 = wq[(size_t)(k0 + kb + 1) * N_DIM + n0 + c];
        int v2 = wq[(size_t)(k0 + kb + 2) * N_DIM + n0 + c];
        int v3 = wq[(size_t)(k0 + kb + 3) * N_DIM + n0 + c];
        lds[c * 17 + (kb >> 2)] =
            (v0 & 255) | ((v1 & 255) << 8) | ((v2 & 255) << 16) | ((v3 & 255) << 24);
    }
    __syncthreads();
    int row = t >> 2;
    int ch = t & 3;
    uint4 o;
    o.x = lds[row * 17 + ch * 4 + 0];
    o.y = lds[row * 17 + ch * 4 + 1];
    o.z = lds[row * 17 + ch * 4 + 2];
    o.w = lds[row * 17 + ch * 4 + 3];
    *(uint4*)(wt + (size_t)(n0 + row) * K_DIM + k0 + ch * 16) = o;
}

// ---------------- 4. int8 MFMA GEMM, 256x256 tile, 8-wave, 4-phase counted-vmcnt ----------------
// BM=BN=256, BK=128 bytes. 8 waves (2M x 4N), per-wave 128x64 output.
// LDS 128 KiB: buf b at b*65536: A[256][128] then B[256][128].
// Swizzle: byte slot (16B units, 8 per row) s' = s ^ (row&7); applied on the
// global SOURCE during global_load_lds staging (linear LDS dest), and on reads.
// Region schedule per iteration i (tile i from buf[i&1]):
//   P0: read A mi0-3 (rows {0-63,128-191}=Ag0) + B ni0-1 (rowmod64<32=Bg0); stage (i+1).Ag1; mfma acc[0-3][0-1]
//   P1: read B ni2-3 (Bg1);                   stage (i+1).Bg1; mfma acc[0-3][2-3]
//   P2: read A mi4-7 (Ag1);                   stage (i+2).Ag0; mfma acc[4-7][2-3]
//   P3: (reg reuse);                          stage (i+2).Bg0; mfma acc[4-7][0-1]
// One vmcnt(4)+barrier at iteration start guarantees all 4 regions of tile i
// (the 4 newest outstanding loads are tile i+1's Ag0/Bg0). vmcnt(0) at last iter.
__global__ __launch_bounds__(512, 2) void gemm8_kernel(
    const char* __restrict__ A, const char* __restrict__ Bt,
    const float* __restrict__ bias, const unsigned* __restrict__ amax,
    float* __restrict__ out) {
    __shared__ char sm[131072];
    const int t = threadIdx.x;
    const int l = t & 63;
    const int w = t >> 6;
    const int wm = w >> 2;
    const int wn = w & 3;
    const int rb = l & 15;
    const int sg = l >> 4;

    int bid = blockIdx.x;
    int swz = (bid & 7) * 64 + (bid >> 3);   // 512 blocks, 8 XCDs, bijective
    int mt = swz >> 4, nt = swz & 15;
    const size_t m0 = (size_t)mt * 256;
    const size_t n0 = (size_t)nt * 256;

    v4i acc[8][4];
#pragma unroll
    for (int i = 0; i < 8; ++i)
#pragma unroll
        for (int j = 0; j < 4; ++j) acc[i][j] = (v4i){0, 0, 0, 0};

#define ST_A(tt, h)                                                          \
    if ((tt) < NT) {                                                         \
        char* lb = sm + (((tt) & 1) * 65536);                                \
        const char* gb = A + m0 * K_DIM + (size_t)(tt) * 128;                \
        _Pragma("unroll")                                                    \
        for (int j = 0; j < 2; ++j) {                                        \
            int p = j * 512 + t;                                             \
            int r7 = p >> 3, sl = p & 7;                                     \
            int r = (r7 & 63) + ((r7 >> 6) << 7) + ((h) << 6);               \
            int s = sl ^ (r & 7);                                            \
            gload16(gb + (size_t)r * K_DIM + s * 16, lb + r * 128 + sl * 16);\
        }                                                                    \
    }
#define ST_B(tt, h)                                                          \
    if ((tt) < NT) {                                                         \
        char* lb = sm + (((tt) & 1) * 65536) + 32768;                        \
        const char* gb = Bt + n0 * K_DIM + (size_t)(tt) * 128;               \
        _Pragma("unroll")                                                    \
        for (int j = 0; j < 2; ++j) {                                        \
            int p = j * 512 + t;                                             \
            int r7 = p >> 3, sl = p & 7;                                     \
            int r = ((r7 >> 5) << 6) + ((h) << 5) + (r7 & 31);               \
            int s = sl ^ (r & 7);                                            \
            gload16(gb + (size_t)r * K_DIM + s * 16, lb + r * 128 + sl * 16);\
        }                                                                    \
    }

    // prologue (oldest->newest): t0.Ag0, t0.Bg0, t0.Ag1, t0.Bg1, t1.Ag0, t1.Bg0
    ST_A(0, 0); ST_B(0, 0); ST_A(0, 1); ST_B(0, 1); ST_A(1, 0); ST_B(1, 0);

    v4i aF[4][2], bF[4][2];

    for (int i = 0; i < NT; ++i) {
        const char* pA = sm + (i & 1) * 65536;
        const char* pB = pA + 32768;
        if (i == NT - 1) { asm volatile("s_waitcnt vmcnt(0)" ::: "memory"); }
        else             { asm volatile("s_waitcnt vmcnt(4)" ::: "memory"); }
        barrier();

        // ---- P0 ----
#pragma unroll
        for (int mi = 0; mi < 4; ++mi)
#pragma unroll
            for (int ks = 0; ks < 2; ++ks) {
                int r = wm * 128 + mi * 16 + rb;
                aF[mi][ks] = *(const v4i*)(pA + r * 128 + (((ks << 2) + sg) ^ (r & 7)) * 16);
            }
#pragma unroll
        for (int ni = 0; ni < 2; ++ni)
#pragma unroll
            for (int ks = 0; ks < 2; ++ks) {
                int r = wn * 64 + ni * 16 + rb;
                bF[ni][ks] = *(const v4i*)(pB + r * 128 + (((ks << 2) + sg) ^ (r & 7)) * 16);
            }
        ST_A(i + 1, 1);
        barrier();
        asm volatile("s_waitcnt lgkmcnt(0)" ::: "memory");
        __builtin_amdgcn_s_setprio(1);
#pragma unroll
        for (int mi = 0; mi < 4; ++mi)
#pragma unroll
            for (int ni = 0; ni < 2; ++ni)
#pragma unroll
                for (int ks = 0; ks < 2; ++ks)
                    acc[mi][ni] = __builtin_amdgcn_mfma_i32_16x16x64_i8(
                        aF[mi][ks], bF[ni][ks], acc[mi][ni], 0, 0, 0);
        __builtin_amdgcn_s_setprio(0);
        barrier();

        // ---- P1 ----
#pragma unroll
        for (int ni = 2; ni < 4; ++ni)
#pragma unroll
            for (int ks = 0; ks < 2; ++ks) {
                int r = wn * 64 + ni * 16 + rb;
                bF[ni][ks] = *(const v4i*)(pB + r * 128 + (((ks << 2) + sg) ^ (r & 7)) * 16);
            }
        ST_B(i + 1, 1);
        barrier();
        asm volatile("s_waitcnt lgkmcnt(0)" ::: "memory");
        __builtin_amdgcn_s_setprio(1);
#pragma unroll
        for (int mi = 0; mi < 4; ++mi)
#pragma unroll
            for (int ni = 2; ni < 4; ++ni)
#pragma unroll
                for (int ks = 0; ks < 2; ++ks)
                    acc[mi][ni] = __builtin_amdgcn_mfma_i32_16x16x64_i8(
                        aF[mi][ks], bF[ni][ks], acc[mi][ni], 0, 0, 0);
        __builtin_amdgcn_s_setprio(0);
        barrier();

        // ---- P2 ----
#pragma unroll
        for (int mi = 0; mi < 4; ++mi)
#pragma unroll
            for (int ks = 0; ks < 2; ++ks) {
                int r = wm * 128 + 64 + mi * 16 + rb;
                aF[mi][ks] = *(const v4i*)(pA + r * 128 + (((ks << 2) + sg) ^ (r & 7)) * 16);
            }
        ST_A(i + 2, 0);
        barrier();
        asm volatile("s_waitcnt lgkmcnt(0)" ::: "memory");
        __builtin_amdgcn_s_setprio(1);
#pragma unroll
        for (int mi = 0; mi < 4; ++mi)
#pragma unroll
            for (int ni = 2; ni < 4; ++ni)
#pragma unroll
                for (int ks = 0; ks < 2; ++ks)
                    acc[mi + 4][ni] = __builtin_amdgcn_mfma_i32_16x16x64_i8(
                        aF[mi][ks], bF[ni][ks], acc[mi + 4][ni], 0, 0, 0);
        __builtin_amdgcn_s_setprio(0);
        barrier();

        // ---- P3 ----
        ST_B(i + 2, 0);
        barrier();
        asm volatile("s_waitcnt lgkmcnt(0)" ::: "memory");
        __builtin_amdgcn_s_setprio(1);
#pragma unroll
        for (int mi = 0; mi < 4; ++mi)
#pragma unroll
            for (int ni = 0; ni < 2; ++ni)
#pragma unroll
                for (int ks = 0; ks < 2; ++ks)
                    acc[mi + 4][ni] = __builtin_amdgcn_mfma_i32_16x16x64_i8(
                        aF[mi][ks], bF[ni][ks], acc[mi + 4][ni], 0, 0, 0);
        __builtin_amdgcn_s_setprio(0);
        barrier();
    }

    // ---- epilogue: dequant + bias ----
    float scale = __uint_as_float(amax[m0 >> 11]) * (1.0f / 128.0f) * 0.01f;
#pragma unroll
    for (int ni = 0; ni < 4; ++ni) {
        int col = (int)n0 + wn * 64 + ni * 16 + rb;
        float bv = bias[col];
#pragma unroll
        for (int mi = 0; mi < 8; ++mi) {
            size_t row = m0 + wm * 128 + mi * 16 + sg * 4;
#pragma unroll
            for (int rg = 0; rg < 4; ++rg)
                out[(row + rg) * N_DIM + col] = (float)acc[mi][ni][rg] * scale + bv;
        }
    }
#undef ST_A
#undef ST_B
}

extern "C" void kernel_launch(void* const* d_in, const int* in_sizes, int n_in,
                              void* d_out, int out_size, void* d_ws, size_t ws_size,
                              hipStream_t stream) {
    const float* x = (const float*)d_in[0];
    const int* wq = (const int*)d_in[1];
    const float* bias = (const float*)d_in[2];
    float* out = (float*)d_out;

    unsigned* amax = (unsigned*)d_ws;
    char* xq = (char*)d_ws + 256;
    char* wt = (char*)d_ws + 256 + (size_t)M_DIM * K_DIM;

    hipMemsetAsync(d_ws, 0, 16, stream);

    wtrans_kernel<<<dim3(64, 64), 256, 0, stream>>>(wq, wt);
    absmax_kernel<<<dim3(1024, 4), 256, 0, stream>>>(x, amax);
    quant_kernel<<<8192, 256, 0, stream>>>(x, amax, xq);
    gemm8_kernel<<<dim3(512), 512, 0, stream>>>(xq, wt, bias, amax, out);
}

// Round 3
// 228.495 us; speedup vs baseline: 1.1594x; 1.0346x over previous
//
#include <hip/hip_runtime.h>
#include <stdint.h>

#define K_DIM 4096
#define N_DIM 4096
#define M_DIM 8192   // B*S = 4*2048
#define S_ROWS 2048
#define NT 32        // K tiles of 128

typedef int v4i __attribute__((ext_vector_type(4)));

__device__ __forceinline__ void gload16(const void* g, void* l) {
    __builtin_amdgcn_global_load_lds(
        (const __attribute__((address_space(1))) unsigned int*)g,
        (__attribute__((address_space(3))) unsigned int*)l, 16, 0, 0);
}

__device__ __forceinline__ void barrier() {
    asm volatile("" ::: "memory");
    __builtin_amdgcn_s_barrier();
    asm volatile("" ::: "memory");
}

// ---------------- 1. per-batch absmax ----------------
__global__ void absmax_kernel(const float* __restrict__ x, unsigned* __restrict__ amax) {
    int b = blockIdx.y;
    const float4* xb = (const float4*)(x + (size_t)b * S_ROWS * K_DIM);
    int tid = blockIdx.x * 256 + threadIdx.x;
    const int stride = 1024 * 256;
    float m = 0.f;
#pragma unroll
    for (int i = 0; i < 8; ++i) {
        float4 v = xb[tid + i * stride];
        m = fmaxf(m, fmaxf(fmaxf(fabsf(v.x), fabsf(v.y)),
                           fmaxf(fabsf(v.z), fabsf(v.w))));
    }
#pragma unroll
    for (int off = 32; off; off >>= 1)
        m = fmaxf(m, __shfl_xor(m, off));
    __shared__ float red[4];
    if ((threadIdx.x & 63) == 0) red[threadIdx.x >> 6] = m;
    __syncthreads();
    if (threadIdx.x == 0) {
        m = fmaxf(fmaxf(red[0], red[1]), fmaxf(red[2], red[3]));
        atomicMax(&amax[b], __float_as_uint(m));
    }
}

// ---------------- 2. quantize x -> int8 ----------------
__global__ void quant_kernel(const float* __restrict__ x,
                             const unsigned* __restrict__ amax,
                             char* __restrict__ xq) {
    size_t gid = (size_t)blockIdx.x * 256 + threadIdx.x;
    size_t base = gid * 16;
    int b = (int)(base >> 23);
    float inv = 128.0f / __uint_as_float(amax[b]);
    const float4* xs = (const float4*)(x + base);
    unsigned parts[4];
#pragma unroll
    for (int i = 0; i < 4; ++i) {
        float4 v = xs[i];
        int q0 = max(-128, min(127, (int)rintf(v.x * inv)));
        int q1 = max(-128, min(127, (int)rintf(v.y * inv)));
        int q2 = max(-128, min(127, (int)rintf(v.z * inv)));
        int q3 = max(-128, min(127, (int)rintf(v.w * inv)));
        parts[i] = (q0 & 255) | ((q1 & 255) << 8) | ((q2 & 255) << 16) | ((q3 & 255) << 24);
    }
    *(uint4*)(xq + base) = make_uint4(parts[0], parts[1], parts[2], parts[3]);
}

// ---------------- 3. weight pack + transpose: int32 [K][N] -> int8 [N][K] ----------------
__global__ void wtrans_kernel(const int* __restrict__ wq, char* __restrict__ wt) {
    __shared__ unsigned lds[64 * 17];
    int t = threadIdx.x;
    int c = t & 63;
    int g = t >> 6;
    int n0 = blockIdx.x * 64;
    int k0 = blockIdx.y * 64;
#pragma unroll
    for (int rep = 0; rep < 4; ++rep) {
        int kb = g * 16 + rep * 4;
        int v0 = wq[(size_t)(k0 + kb + 0) * N_DIM + n0 + c];
        int v1 = wq[(size_t)(k0 + kb + 1) * N_DIM + n0 + c];
        int v2 = wq[(size_t)(k0 + kb + 2) * N_DIM + n0 + c];
        int v3 = wq[(size_t)(k0 + kb + 3) * N_DIM + n0 + c];
        lds[c * 17 + (kb >> 2)] =
            (v0 & 255) | ((v1 & 255) << 8) | ((v2 & 255) << 16) | ((v3 & 255) << 24);
    }
    __syncthreads();
    int row = t >> 2;
    int ch = t & 3;
    uint4 o;
    o.x = lds[row * 17 + ch * 4 + 0];
    o.y = lds[row * 17 + ch * 4 + 1];
    o.z = lds[row * 17 + ch * 4 + 2];
    o.w = lds[row * 17 + ch * 4 + 3];
    *(uint4*)(wt + (size_t)(n0 + row) * K_DIM + k0 + ch * 16) = o;
}

// ---------------- 4. int8 MFMA GEMM, 256x256 tile, 8-wave, 2-barrier K-loop ----------------
// BM=BN=256, BK=128 bytes. 8 waves (2M x 4N), per-wave 128x64 output.
// LDS 128 KiB: buf b at b*65536: A[256][128] then B[256][128].
// Swizzle: 16B slot s' = s ^ (row&7), applied to the global SOURCE (linear LDS
// dest, rule #21) and on ds_read addresses. 0 bank conflicts measured.
// Minimal-sync K-loop (2 barriers/K-tile):
//   top: vmcnt(4) [vmcnt(0) last iter]; barrier      -- tile i certified in LDS
//   reads aF=Ag0(8), bF01=Bg0(4); stage (i+1).Ag1,(i+1).Bg1 (other buffer)
//   MFMA P0 (aF x bF01); reads bF23(4); MFMA P1 (aF x bF23)
//   barrier                                           -- all waves consumed Ag0/Bg0 reads
//   reads aF=Ag1(8); stage (i+2).Ag0,(i+2).Bg0 (overwrites regions dead since P0/P1)
//   MFMA P2 (aF x bF23); MFMA P3 (aF x bF01)
// Stage issue order Ag1,Bg1,Ag0',Bg0' keeps vmcnt(4) = "tile i+1 fully landed".
// No inline lgkmcnt: compiler emits fine-grained lgkmcnt(N) per fragment use.
__global__ __launch_bounds__(512, 2) void gemm8_kernel(
    const char* __restrict__ A, const char* __restrict__ Bt,
    const float* __restrict__ bias, const unsigned* __restrict__ amax,
    float* __restrict__ out) {
    __shared__ char sm[131072];
    const int t = threadIdx.x;
    const int l = t & 63;
    const int w = t >> 6;
    const int wm = w >> 2;
    const int wn = w & 3;
    const int rb = l & 15;
    const int sg = l >> 4;

    int bid = blockIdx.x;
    int swz = (bid & 7) * 64 + (bid >> 3);   // 512 blocks, 8 XCDs, bijective
    int mt = swz >> 4, nt = swz & 15;
    const size_t m0 = (size_t)mt * 256;
    const size_t n0 = (size_t)nt * 256;

    v4i acc[8][4];
#pragma unroll
    for (int i = 0; i < 8; ++i)
#pragma unroll
        for (int j = 0; j < 4; ++j) acc[i][j] = (v4i){0, 0, 0, 0};

#define ST_A(tt, h)                                                          \
    if ((tt) < NT) {                                                         \
        char* lb = sm + (((tt) & 1) * 65536);                                \
        const char* gb = A + m0 * K_DIM + (size_t)(tt) * 128;                \
        _Pragma("unroll")                                                    \
        for (int j = 0; j < 2; ++j) {                                        \
            int p = j * 512 + t;                                             \
            int r7 = p >> 3, sl = p & 7;                                     \
            int r = (r7 & 63) + ((r7 >> 6) << 7) + ((h) << 6);               \
            int s = sl ^ (r & 7);                                            \
            gload16(gb + (size_t)r * K_DIM + s * 16, lb + r * 128 + sl * 16);\
        }                                                                    \
    }
#define ST_B(tt, h)                                                          \
    if ((tt) < NT) {                                                         \
        char* lb = sm + (((tt) & 1) * 65536) + 32768;                        \
        const char* gb = Bt + n0 * K_DIM + (size_t)(tt) * 128;               \
        _Pragma("unroll")                                                    \
        for (int j = 0; j < 2; ++j) {                                        \
            int p = j * 512 + t;                                             \
            int r7 = p >> 3, sl = p & 7;                                     \
            int r = ((r7 >> 5) << 6) + ((h) << 5) + (r7 & 31);               \
            int s = sl ^ (r & 7);                                            \
            gload16(gb + (size_t)r * K_DIM + s * 16, lb + r * 128 + sl * 16);\
        }                                                                    \
    }

    // prologue (oldest->newest): t0.Ag0, t0.Bg0, t0.Ag1, t0.Bg1, t1.Ag0, t1.Bg0
    ST_A(0, 0); ST_B(0, 0); ST_A(0, 1); ST_B(0, 1); ST_A(1, 0); ST_B(1, 0);

    v4i aF[4][2], bL[2][2], bH[2][2];

    for (int i = 0; i < NT; ++i) {
        const char* pA = sm + (i & 1) * 65536;
        const char* pB = pA + 32768;
        if (i == NT - 1) { asm volatile("s_waitcnt vmcnt(0)" ::: "memory"); }
        else             { asm volatile("s_waitcnt vmcnt(4)" ::: "memory"); }
        barrier();

        // ---- region 1: P0 + P1 ----
#pragma unroll
        for (int mi = 0; mi < 4; ++mi)
#pragma unroll
            for (int ks = 0; ks < 2; ++ks) {
                int r = wm * 128 + mi * 16 + rb;
                aF[mi][ks] = *(const v4i*)(pA + r * 128 + (((ks << 2) + sg) ^ (r & 7)) * 16);
            }
#pragma unroll
        for (int ni = 0; ni < 2; ++ni)
#pragma unroll
            for (int ks = 0; ks < 2; ++ks) {
                int r = wn * 64 + ni * 16 + rb;
                bL[ni][ks] = *(const v4i*)(pB + r * 128 + (((ks << 2) + sg) ^ (r & 7)) * 16);
            }
        ST_A(i + 1, 1);
        ST_B(i + 1, 1);
        __builtin_amdgcn_s_setprio(1);
#pragma unroll
        for (int mi = 0; mi < 4; ++mi)
#pragma unroll
            for (int ni = 0; ni < 2; ++ni)
#pragma unroll
                for (int ks = 0; ks < 2; ++ks)
                    acc[mi][ni] = __builtin_amdgcn_mfma_i32_16x16x64_i8(
                        aF[mi][ks], bL[ni][ks], acc[mi][ni], 0, 0, 0);
#pragma unroll
        for (int ni = 0; ni < 2; ++ni)
#pragma unroll
            for (int ks = 0; ks < 2; ++ks) {
                int r = wn * 64 + 32 + ni * 16 + rb;
                bH[ni][ks] = *(const v4i*)(pB + r * 128 + (((ks << 2) + sg) ^ (r & 7)) * 16);
            }
#pragma unroll
        for (int mi = 0; mi < 4; ++mi)
#pragma unroll
            for (int ni = 0; ni < 2; ++ni)
#pragma unroll
                for (int ks = 0; ks < 2; ++ks)
                    acc[mi][ni + 2] = __builtin_amdgcn_mfma_i32_16x16x64_i8(
                        aF[mi][ks], bH[ni][ks], acc[mi][ni + 2], 0, 0, 0);
        __builtin_amdgcn_s_setprio(0);
        barrier();

        // ---- region 2: P2 + P3 ----
#pragma unroll
        for (int mi = 0; mi < 4; ++mi)
#pragma unroll
            for (int ks = 0; ks < 2; ++ks) {
                int r = wm * 128 + 64 + mi * 16 + rb;
                aF[mi][ks] = *(const v4i*)(pA + r * 128 + (((ks << 2) + sg) ^ (r & 7)) * 16);
            }
        ST_A(i + 2, 0);
        ST_B(i + 2, 0);
        __builtin_amdgcn_s_setprio(1);
#pragma unroll
        for (int mi = 0; mi < 4; ++mi)
#pragma unroll
            for (int ni = 0; ni < 2; ++ni)
#pragma unroll
                for (int ks = 0; ks < 2; ++ks)
                    acc[mi + 4][ni + 2] = __builtin_amdgcn_mfma_i32_16x16x64_i8(
                        aF[mi][ks], bH[ni][ks], acc[mi + 4][ni + 2], 0, 0, 0);
#pragma unroll
        for (int mi = 0; mi < 4; ++mi)
#pragma unroll
            for (int ni = 0; ni < 2; ++ni)
#pragma unroll
                for (int ks = 0; ks < 2; ++ks)
                    acc[mi + 4][ni] = __builtin_amdgcn_mfma_i32_16x16x64_i8(
                        aF[mi][ks], bL[ni][ks], acc[mi + 4][ni], 0, 0, 0);
        __builtin_amdgcn_s_setprio(0);
    }

    // ---- epilogue: dequant + bias, row-major store order for write coalescing ----
    float scale = __uint_as_float(amax[m0 >> 11]) * (1.0f / 128.0f) * 0.01f;
    float bv[4];
#pragma unroll
    for (int ni = 0; ni < 4; ++ni) bv[ni] = bias[n0 + wn * 64 + ni * 16 + rb];
#pragma unroll
    for (int mi = 0; mi < 8; ++mi) {
#pragma unroll
        for (int rg = 0; rg < 4; ++rg) {
            size_t row = m0 + wm * 128 + mi * 16 + sg * 4 + rg;
            float* orow = out + row * N_DIM + n0 + wn * 64 + rb;
#pragma unroll
            for (int ni = 0; ni < 4; ++ni)
                orow[ni * 16] = (float)acc[mi][ni][rg] * scale + bv[ni];
        }
    }
#undef ST_A
#undef ST_B
}

extern "C" void kernel_launch(void* const* d_in, const int* in_sizes, int n_in,
                              void* d_out, int out_size, void* d_ws, size_t ws_size,
                              hipStream_t stream) {
    const float* x = (const float*)d_in[0];
    const int* wq = (const int*)d_in[1];
    const float* bias = (const float*)d_in[2];
    float* out = (float*)d_out;

    unsigned* amax = (unsigned*)d_ws;
    char* xq = (char*)d_ws + 256;
    char* wt = (char*)d_ws + 256 + (size_t)M_DIM * K_DIM;

    hipMemsetAsync(d_ws, 0, 16, stream);

    wtrans_kernel<<<dim3(64, 64), 256, 0, stream>>>(wq, wt);
    absmax_kernel<<<dim3(1024, 4), 256, 0, stream>>>(x, amax);
    quant_kernel<<<8192, 256, 0, stream>>>(x, amax, xq);
    gemm8_kernel<<<dim3(512), 512, 0, stream>>>(xq, wt, bias, amax, out);
}

// Round 4
// 218.463 us; speedup vs baseline: 1.2126x; 1.0459x over previous
//
#include <hip/hip_runtime.h>
#include <stdint.h>

#define K_DIM 4096
#define N_DIM 4096
#define M_DIM 8192   // B*S = 4*2048
#define S_ROWS 2048
#define NT 32        // K tiles of 128 bytes

typedef int v4i __attribute__((ext_vector_type(4)));

__device__ __forceinline__ void gload16(const void* g, void* l) {
    __builtin_amdgcn_global_load_lds(
        (const __attribute__((address_space(1))) unsigned int*)g,
        (__attribute__((address_space(3))) unsigned int*)l, 16, 0, 0);
}

__device__ __forceinline__ void barrier() {
    asm volatile("" ::: "memory");
    __builtin_amdgcn_s_barrier();
    asm volatile("" ::: "memory");
}

// ---------------- 1. fused prep: absmax (blocks 0..4095) + wtrans (4096..8191) ----------------
__global__ void prep1_kernel(const float* __restrict__ x, unsigned* __restrict__ amax,
                             const int* __restrict__ wq, char* __restrict__ wt) {
    __shared__ unsigned lds[64 * 17];
    if (blockIdx.x < 4096) {
        // ---- absmax over batch b ----
        int b = blockIdx.x >> 10;
        int bx = blockIdx.x & 1023;
        const float4* xb = (const float4*)(x + (size_t)b * S_ROWS * K_DIM);
        int tid = bx * 256 + threadIdx.x;
        const int stride = 1024 * 256;
        float m = 0.f;
#pragma unroll
        for (int i = 0; i < 8; ++i) {
            float4 v = xb[tid + i * stride];
            m = fmaxf(m, fmaxf(fmaxf(fabsf(v.x), fabsf(v.y)),
                               fmaxf(fabsf(v.z), fabsf(v.w))));
        }
#pragma unroll
        for (int off = 32; off; off >>= 1)
            m = fmaxf(m, __shfl_xor(m, off));
        float* red = (float*)lds;
        if ((threadIdx.x & 63) == 0) red[threadIdx.x >> 6] = m;
        __syncthreads();
        if (threadIdx.x == 0) {
            m = fmaxf(fmaxf(red[0], red[1]), fmaxf(red[2], red[3]));
            atomicMax(&amax[b], __float_as_uint(m));
        }
    } else {
        // ---- weight transpose+pack: int32 [K][N] -> int8 [N][K] ----
        int wb = blockIdx.x - 4096;
        int n0 = (wb & 63) * 64;
        int k0 = (wb >> 6) * 64;
        int t = threadIdx.x;
        int c = t & 63;
        int g = t >> 6;
#pragma unroll
        for (int rep = 0; rep < 4; ++rep) {
            int kb = g * 16 + rep * 4;
            int v0 = wq[(size_t)(k0 + kb + 0) * N_DIM + n0 + c];
            int v1 = wq[(size_t)(k0 + kb + 1) * N_DIM + n0 + c];
            int v2 = wq[(size_t)(k0 + kb + 2) * N_DIM + n0 + c];
            int v3 = wq[(size_t)(k0 + kb + 3) * N_DIM + n0 + c];
            lds[c * 17 + (kb >> 2)] =
                (v0 & 255) | ((v1 & 255) << 8) | ((v2 & 255) << 16) | ((v3 & 255) << 24);
        }
        __syncthreads();
        int row = t >> 2;
        int ch = t & 3;
        uint4 o;
        o.x = lds[row * 17 + ch * 4 + 0];
        o.y = lds[row * 17 + ch * 4 + 1];
        o.z = lds[row * 17 + ch * 4 + 2];
        o.w = lds[row * 17 + ch * 4 + 3];
        *(uint4*)(wt + (size_t)(n0 + row) * K_DIM + k0 + ch * 16) = o;
    }
}

// ---------------- 2. quantize x -> int8 ----------------
__global__ void quant_kernel(const float* __restrict__ x,
                             const unsigned* __restrict__ amax,
                             char* __restrict__ xq) {
    size_t gid = (size_t)blockIdx.x * 256 + threadIdx.x;
    size_t base = gid * 16;
    int b = (int)(base >> 23);
    float inv = 128.0f / __uint_as_float(amax[b]);
    const float4* xs = (const float4*)(x + base);
    unsigned parts[4];
#pragma unroll
    for (int i = 0; i < 4; ++i) {
        float4 v = xs[i];
        int q0 = max(-128, min(127, (int)rintf(v.x * inv)));
        int q1 = max(-128, min(127, (int)rintf(v.y * inv)));
        int q2 = max(-128, min(127, (int)rintf(v.z * inv)));
        int q3 = max(-128, min(127, (int)rintf(v.w * inv)));
        parts[i] = (q0 & 255) | ((q1 & 255) << 8) | ((q2 & 255) << 16) | ((q3 & 255) << 24);
    }
    *(uint4*)(xq + base) = make_uint4(parts[0], parts[1], parts[2], parts[3]);
}

// ---------------- 3. int8 MFMA GEMM, 256x256 tile, 8-wave, 1-barrier K-loop ----------------
// BM=BN=256, BK=128 bytes. 8 waves (2M x 4N), per-wave 128x64 output.
// LDS 128 KiB double buffer: buf b at b*65536: A[256][128] then B[256][128].
// Swizzle: 16B slot s' = s ^ (row&7) applied to the global SOURCE (linear LDS
// dest, rule #21) and on read addresses. row&7 == rb&7 for every fragment row,
// so all 24 reads/tile reduce to 4 pointers + compile-time immediates.
// Pipeline: 1-tile-ahead staging into the OTHER buffer -> no intra-iteration
// overwrite hazard -> single barrier + single vmcnt(0) per K-tile. ST(i+1)
// (issued post-barrier in iter i) vs tile-(i-1) reads (consumed by iter-(i-1)
// MFMAs before that barrier) is ordered by the same barrier.
__global__ __launch_bounds__(512, 2) void gemm8_kernel(
    const char* __restrict__ A, const char* __restrict__ Bt,
    const float* __restrict__ bias, const unsigned* __restrict__ amax,
    float* __restrict__ out) {
    __shared__ char sm[131072];
    const int t = threadIdx.x;
    const int l = t & 63;
    const int w = t >> 6;
    const int wm = w >> 2;
    const int wn = w & 3;
    const int rb = l & 15;
    const int sg = l >> 4;

    int bid = blockIdx.x;
    int swz = (bid & 7) * 64 + (bid >> 3);   // 512 blocks, 8 XCDs, bijective
    int mt = swz >> 4, nt = swz & 15;
    const size_t m0 = (size_t)mt * 256;
    const size_t n0 = (size_t)nt * 256;

    // precomputed read bases: slot xor depends only on rb&7 and sg
    const int s0 = (sg ^ (rb & 7)) << 4;     // ks=0 slot byte offset
    const int s1 = s0 ^ 64;                  // ks=1
    const int baseA = (wm * 128 + rb) * 128;
    const int baseB = 32768 + (wn * 64 + rb) * 128;

    v4i acc[8][4];
#pragma unroll
    for (int i = 0; i < 8; ++i)
#pragma unroll
        for (int j = 0; j < 4; ++j) acc[i][j] = (v4i){0, 0, 0, 0};

#define ST_FULL(tt)                                                          \
    if ((tt) < NT) {                                                         \
        char* lb = sm + (((tt) & 1) << 16);                                  \
        const char* ga = A + m0 * K_DIM + (size_t)(tt) * 128;                \
        const char* gb = Bt + n0 * K_DIM + (size_t)(tt) * 128;               \
        _Pragma("unroll")                                                    \
        for (int j = 0; j < 4; ++j) {                                        \
            int p = j * 512 + t;                                             \
            int r = p >> 3, sl = p & 7;                                      \
            int s = sl ^ (r & 7);                                            \
            gload16(ga + (size_t)r * K_DIM + s * 16, lb + p * 16);           \
        }                                                                    \
        _Pragma("unroll")                                                    \
        for (int j = 0; j < 4; ++j) {                                        \
            int p = j * 512 + t;                                             \
            int r = p >> 3, sl = p & 7;                                      \
            int s = sl ^ (r & 7);                                            \
            gload16(gb + (size_t)r * K_DIM + s * 16, lb + 32768 + p * 16);   \
        }                                                                    \
    }

    // prologue: stage tile 0
    ST_FULL(0);

    v4i aF[4][2], aG[4][2], bF[4][2];

    for (int i = 0; i < NT; ++i) {
        const char* pb = sm + ((i & 1) << 16);
        const char* pA0 = pb + baseA + s0;
        const char* pA1 = pb + baseA + s1;
        const char* pB0 = pb + baseB + s0;
        const char* pB1 = pb + baseB + s1;

        asm volatile("s_waitcnt vmcnt(0)" ::: "memory");
        barrier();

        // all 24 fragment reads: pointer + compile-time immediate
#pragma unroll
        for (int mi = 0; mi < 4; ++mi) {
            aF[mi][0] = *(const v4i*)(pA0 + mi * 2048);
            aF[mi][1] = *(const v4i*)(pA1 + mi * 2048);
        }
#pragma unroll
        for (int ni = 0; ni < 4; ++ni) {
            bF[ni][0] = *(const v4i*)(pB0 + ni * 2048);
            bF[ni][1] = *(const v4i*)(pB1 + ni * 2048);
        }
#pragma unroll
        for (int mi = 0; mi < 4; ++mi) {
            aG[mi][0] = *(const v4i*)(pA0 + mi * 2048 + 8192);
            aG[mi][1] = *(const v4i*)(pA1 + mi * 2048 + 8192);
        }

        // stage next tile into the other buffer (no hazard with this tile)
        ST_FULL(i + 1);

        __builtin_amdgcn_s_setprio(1);
#pragma unroll
        for (int mi = 0; mi < 4; ++mi)
#pragma unroll
            for (int ni = 0; ni < 4; ++ni)
#pragma unroll
                for (int ks = 0; ks < 2; ++ks)
                    acc[mi][ni] = __builtin_amdgcn_mfma_i32_16x16x64_i8(
                        aF[mi][ks], bF[ni][ks], acc[mi][ni], 0, 0, 0);
#pragma unroll
        for (int mi = 0; mi < 4; ++mi)
#pragma unroll
            for (int ni = 0; ni < 4; ++ni)
#pragma unroll
                for (int ks = 0; ks < 2; ++ks)
                    acc[mi + 4][ni] = __builtin_amdgcn_mfma_i32_16x16x64_i8(
                        aG[mi][ks], bF[ni][ks], acc[mi + 4][ni], 0, 0, 0);
        __builtin_amdgcn_s_setprio(0);
    }

    // ---- epilogue: dequant + bias, row-major store order ----
    float scale = __uint_as_float(amax[m0 >> 11]) * (1.0f / 128.0f) * 0.01f;
    float bv[4];
#pragma unroll
    for (int ni = 0; ni < 4; ++ni) bv[ni] = bias[n0 + wn * 64 + ni * 16 + rb];
#pragma unroll
    for (int mi = 0; mi < 8; ++mi) {
#pragma unroll
        for (int rg = 0; rg < 4; ++rg) {
            size_t row = m0 + wm * 128 + mi * 16 + sg * 4 + rg;
            float* orow = out + row * N_DIM + n0 + wn * 64 + rb;
#pragma unroll
            for (int ni = 0; ni < 4; ++ni)
                orow[ni * 16] = (float)acc[mi][ni][rg] * scale + bv[ni];
        }
    }
#undef ST_FULL
}

extern "C" void kernel_launch(void* const* d_in, const int* in_sizes, int n_in,
                              void* d_out, int out_size, void* d_ws, size_t ws_size,
                              hipStream_t stream) {
    const float* x = (const float*)d_in[0];
    const int* wq = (const int*)d_in[1];
    const float* bias = (const float*)d_in[2];
    float* out = (float*)d_out;

    unsigned* amax = (unsigned*)d_ws;
    char* xq = (char*)d_ws + 256;
    char* wt = (char*)d_ws + 256 + (size_t)M_DIM * K_DIM;

    hipMemsetAsync(d_ws, 0, 16, stream);

    prep1_kernel<<<dim3(8192), 256, 0, stream>>>(x, amax, wq, wt);
    quant_kernel<<<8192, 256, 0, stream>>>(x, amax, xq);
    gemm8_kernel<<<dim3(512), 512, 0, stream>>>(xq, wt, bias, amax, out);
}